// Round 10
// baseline (8861.264 us; speedup 1.0000x reference)
//
#include <hip/hip_runtime.h>

// Two-layer tanh RNN, persistent kernel (plain launch), MFMA bf16, epoch sync.
// Round-10: fat WGs to cut MALL flag contention.
// 64 WGs x 512 thr (8 waves): wg = layer*32 + m_blk*16 + n_blk.
//   WG = 64 feats x 32 rows. Wave wv: fg=wv>>1 (16-feat slice), kh=wv&1 (K half).
//   Each wave does BOTH sources (x/h1[s] via wregA, h-prev via wregB) into one
//   acc -> cross-wave reduce is only over kh (2 partials). 128 VGPR weights.
// Producer group per (layer,m_blk) = 16 WGs -> poll = 4 dwordx4 of one 64B line.
// ONE poller per WG (tid0) + __syncthreads (was: per-wave lane0, 16-load scans).
// Rings 8-deep. Rule-18: sched_barrier(0) after every inline-asm vmcnt wait.
//   L0@s: tid0 waits grpL1>=s-7 (WAR), grpL0>=s (h1[s-1]); barrier; h-part.
//   L1@s: tid0 waits grpL1>=s; barrier; h2-part; tid0 waits grpL0>=s+1; barrier;
//         h1[s]-part (critical).

#define SEQ 512
#define BATCH 64
#define HID 1024
#define BH (BATCH * HID)
#define DEPTH 8

typedef __attribute__((ext_vector_type(8))) short short8;
typedef __attribute__((ext_vector_type(4))) float f32x4;
typedef __attribute__((ext_vector_type(4))) unsigned int u32x4;

__device__ __forceinline__ unsigned short f32_to_bf16_rne(float f) {
    unsigned int u = __float_as_uint(f);
    u += 0x7FFFu + ((u >> 16) & 1u);
    return (unsigned short)(u >> 16);
}

__device__ __forceinline__ short8 cvt8(float4 f0, float4 f1) {
    short8 w;
    w[0] = (short)f32_to_bf16_rne(f0.x);
    w[1] = (short)f32_to_bf16_rne(f0.y);
    w[2] = (short)f32_to_bf16_rne(f0.z);
    w[3] = (short)f32_to_bf16_rne(f0.w);
    w[4] = (short)f32_to_bf16_rne(f1.x);
    w[5] = (short)f32_to_bf16_rne(f1.y);
    w[6] = (short)f32_to_bf16_rne(f1.z);
    w[7] = (short)f32_to_bf16_rne(f1.w);
    return w;
}

// 16B device-coherent load (served at MALL), pipelineable; caller waits.
__device__ __forceinline__ void ld_cc16(short8& d, const unsigned short* p) {
    asm volatile("global_load_dwordx4 %0, %1, off sc0 sc1"
                 : "=v"(d) : "v"(p) : "memory");
}

__device__ __forceinline__ void vm_wait0() {
    asm volatile("s_waitcnt vmcnt(0)" ::: "memory");
    __builtin_amdgcn_sched_barrier(0);   // rule 18
}

__device__ __forceinline__ unsigned long long pack4_bf16(float a, float b, float c, float d) {
    return (unsigned long long)f32_to_bf16_rne(a)
         | ((unsigned long long)f32_to_bf16_rne(b) << 16)
         | ((unsigned long long)f32_to_bf16_rne(c) << 32)
         | ((unsigned long long)f32_to_bf16_rne(d) << 48);
}

// min over 16 epoch slots (64B): 4 pipelined coherent loads + one wait.
// RULE-18: sched_barrier(0) after the waitcnt (r8's race).
__device__ __forceinline__ int poll_min16(const unsigned int* f) {
    u32x4 r[4];
    #pragma unroll
    for (int i = 0; i < 4; ++i)
        asm volatile("global_load_dwordx4 %0, %1, off sc0 sc1"
                     : "=v"(r[i]) : "v"(f + i * 4) : "memory");
    asm volatile("s_waitcnt vmcnt(0)" ::: "memory");
    __builtin_amdgcn_sched_barrier(0);
    unsigned mn = r[0][0];
    #pragma unroll
    for (int i = 0; i < 4; ++i)
        #pragma unroll
        for (int j = 0; j < 4; ++j)
            mn = mn < r[i][j] ? mn : r[i][j];
    return (int)mn;
}

__device__ __forceinline__ void wait_min16(const unsigned int* f, int target) {
    if (target <= 0) return;
    while (poll_min16(f) < target) __builtin_amdgcn_s_sleep(1);
}

__global__ void cvt_f32_bf16(const float* __restrict__ src,
                             unsigned short* __restrict__ dst, int n4) {
    int i = blockIdx.x * blockDim.x + threadIdx.x;
    int stride = gridDim.x * blockDim.x;
    for (; i < n4; i += stride) {
        float4 f = ((const float4*)src)[i];
        ushort4 o;
        o.x = f32_to_bf16_rne(f.x);
        o.y = f32_to_bf16_rne(f.y);
        o.z = f32_to_bf16_rne(f.z);
        o.w = f32_to_bf16_rne(f.w);
        ((ushort4*)dst)[i] = o;
    }
}

__global__ void init_ws(uint4* __restrict__ p, int n16) {
    int i = blockIdx.x * blockDim.x + threadIdx.x;
    if (i < n16) p[i] = make_uint4(0u, 0u, 0u, 0u);
}

#define MFMA16(W, A, ACC) \
    ACC = __builtin_amdgcn_mfma_f32_16x16x32_bf16((W), (A), (ACC), 0, 0, 0)

__global__ __launch_bounds__(512, 1) void rnn_mfma(
    const float* __restrict__ x,
    const unsigned short* __restrict__ xb, int use_xb,
    const float* __restrict__ Wi0, const float* __restrict__ bi0,
    const float* __restrict__ Wh0, const float* __restrict__ bh0,
    const float* __restrict__ Wi1, const float* __restrict__ bi1,
    const float* __restrict__ Wh1, const float* __restrict__ bh1,
    float* __restrict__ out,
    unsigned short* __restrict__ rings,
    unsigned int* __restrict__ flags)
{
    unsigned short* h1ring = rings;                  // [8][64][1024] bf16
    unsigned short* h2ring = rings + DEPTH * BH;     // [8][64][1024] bf16

    const int tid   = threadIdx.x;
    const int wg    = blockIdx.x;        // 0..63
    const int layer = wg >> 5;           // 0/1
    const int m_blk = (wg >> 4) & 1;     // 0/1 (32 rows)
    const int n_blk = wg & 15;           // 0..15 (64 feats)
    const int wv    = tid >> 6;          // 0..7
    const int lane  = tid & 63;
    const int fg    = wv >> 1;           // 0..3: 16-feat slice
    const int kh    = wv & 1;            // K half

    unsigned int* grpL0 = flags + (0 * 2 + m_blk) * 64;   // 256B-spaced groups
    unsigned int* grpL1 = flags + (1 * 2 + m_blk) * 64;
    unsigned int* ep_self = (layer ? grpL1 : grpL0) + n_blk;

    // ---- resident weights: both sources, 2 x 16 short8 = 128 VGPRs ----
    const int f_w = n_blk * 64 + fg * 16 + (lane & 15);
    const int kcb = kh * 512 + (lane >> 4) * 8;
    const float* WA = layer ? Wi1 : Wi0;   // first source (x or h1[s])
    const float* WB = layer ? Wh1 : Wh0;   // recurrent source
    short8 wregA[16], wregB[16];
    {
        const float* ra = WA + (size_t)f_w * HID + kcb;
        const float* rb = WB + (size_t)f_w * HID + kcb;
        #pragma unroll
        for (int ks = 0; ks < 16; ++ks) {
            wregA[ks] = cvt8(*(const float4*)(ra + ks * 32),
                             *(const float4*)(ra + ks * 32 + 4));
            wregB[ks] = cvt8(*(const float4*)(rb + ks * 32),
                             *(const float4*)(rb + ks * 32 + 4));
        }
    }

    // activation (B-operand) addresses
    const int arow0 = m_blk * 32 + (lane & 15);
    const int arow1 = arow0 + 16;
    const size_t aoff0 = (size_t)arow0 * HID + kcb;
    const size_t aoff1 = (size_t)arow1 * HID + kcb;

    // reduce-phase constants: 512 threads, one (4-feat, row) pack each
    const int r_row = tid & 31;          // 0..31
    const int r_f4  = tid >> 5;          // 0..15
    const int nb    = n_blk * 64 + r_f4 * 4;
    const int rg    = m_blk * 32 + r_row;
    const float* biv = layer ? bi1 : bi0;
    const float* bhv = layer ? bh1 : bh0;
    float bias4[4];
    #pragma unroll
    for (int j = 0; j < 4; ++j) bias4[j] = biv[nb + j] + bhv[nb + j];

    __shared__ float red[8][16][33];     // 16.9 KB

    for (int s = 0; s < SEQ; ++s) {
        f32x4 acc0 = {0.f, 0.f, 0.f, 0.f};
        f32x4 acc1 = {0.f, 0.f, 0.f, 0.f};

        if (layer == 0) {
            // ---- x_s @ Wi0^T : static input, plain loads, before the wait ----
            if (use_xb) {
                const unsigned short* px = xb + (size_t)s * BH;
                #pragma unroll
                for (int ks = 0; ks < 16; ++ks) {
                    short8 a0 = *(const short8*)(px + aoff0 + ks * 32);
                    short8 a1 = *(const short8*)(px + aoff1 + ks * 32);
                    MFMA16(wregA[ks], a0, acc0);
                    MFMA16(wregA[ks], a1, acc1);
                }
            } else {
                const float* px = x + (size_t)s * BH;
                #pragma unroll
                for (int ks = 0; ks < 16; ++ks) {
                    short8 a0 = cvt8(*(const float4*)(px + aoff0 + ks * 32),
                                     *(const float4*)(px + aoff0 + ks * 32 + 4));
                    short8 a1 = cvt8(*(const float4*)(px + aoff1 + ks * 32),
                                     *(const float4*)(px + aoff1 + ks * 32 + 4));
                    MFMA16(wregA[ks], a0, acc0);
                    MFMA16(wregA[ks], a1, acc1);
                }
            }
            // ---- wait (tid0 only): WAR first, then data ----
            if (tid == 0) {
                wait_min16(grpL1, s - (DEPTH - 1));   // L1 consumed h1[s-DEPTH]
                wait_min16(grpL0, s);                 // h1[s-1] complete
            }
            __syncthreads();
            // ---- critical: h1[s-1] @ Wh0^T ----
            const unsigned short* pr = h1ring + (size_t)((s - 1) & (DEPTH - 1)) * BH;
            #pragma unroll
            for (int c = 0; c < 2; ++c) {
                short8 a0[8], a1[8];
                #pragma unroll
                for (int k = 0; k < 8; ++k) {
                    ld_cc16(a0[k], pr + aoff0 + (c * 8 + k) * 32);
                    ld_cc16(a1[k], pr + aoff1 + (c * 8 + k) * 32);
                }
                vm_wait0();
                #pragma unroll
                for (int k = 0; k < 8; ++k) {
                    MFMA16(wregB[c * 8 + k], a0[k], acc0);
                    MFMA16(wregB[c * 8 + k], a1[k], acc1);
                }
            }
        } else {
            // ---- wait1 (usually satisfied): h2[s-1] done ----
            if (tid == 0) wait_min16(grpL1, s);
            __syncthreads();
            // ---- early: h2[s-1] @ Wh1^T ----
            const unsigned short* pr2 = h2ring + (size_t)((s - 1) & (DEPTH - 1)) * BH;
            #pragma unroll
            for (int c = 0; c < 2; ++c) {
                short8 a0[8], a1[8];
                #pragma unroll
                for (int k = 0; k < 8; ++k) {
                    ld_cc16(a0[k], pr2 + aoff0 + (c * 8 + k) * 32);
                    ld_cc16(a1[k], pr2 + aoff1 + (c * 8 + k) * 32);
                }
                vm_wait0();
                #pragma unroll
                for (int k = 0; k < 8; ++k) {
                    MFMA16(wregB[c * 8 + k], a0[k], acc0);
                    MFMA16(wregB[c * 8 + k], a1[k], acc1);
                }
            }
            // ---- wait2 (critical): h1[s] done ----
            if (tid == 0) wait_min16(grpL0, s + 1);
            __syncthreads();
            // ---- critical: h1[s] @ Wi1^T ----
            const unsigned short* pr1 = h1ring + (size_t)(s & (DEPTH - 1)) * BH;
            #pragma unroll
            for (int c = 0; c < 2; ++c) {
                short8 a0[8], a1[8];
                #pragma unroll
                for (int k = 0; k < 8; ++k) {
                    ld_cc16(a0[k], pr1 + aoff0 + (c * 8 + k) * 32);
                    ld_cc16(a1[k], pr1 + aoff1 + (c * 8 + k) * 32);
                }
                vm_wait0();
                #pragma unroll
                for (int k = 0; k < 8; ++k) {
                    MFMA16(wregA[c * 8 + k], a0[k], acc0);
                    MFMA16(wregA[c * 8 + k], a1[k], acc1);
                }
            }
        }

        // ---- partials to LDS: red[wave][feat][row] ----
        #pragma unroll
        for (int r = 0; r < 4; ++r) {
            red[wv][4 * (lane >> 4) + r][lane & 15]        = acc0[r];
            red[wv][4 * (lane >> 4) + r][16 + (lane & 15)] = acc1[r];
        }
        __syncthreads();

        // ---- reduce (2 kh partials) + tanh + ring store: all 512 threads ----
        float v[4];
        {
            #pragma unroll
            for (int j = 0; j < 4; ++j) {
                const int f   = r_f4 * 4 + j;
                const int fgi = f >> 4;
                const int ff  = f & 15;
                float sum = red[2 * fgi][ff][r_row] + red[2 * fgi + 1][ff][r_row]
                          + bias4[j];
                v[j] = tanhf(sum);
            }
            unsigned short* ring_self =
                (layer ? h2ring : h1ring) + (size_t)(s & (DEPTH - 1)) * BH;
            __hip_atomic_store((unsigned long long*)(ring_self + (size_t)rg * HID + nb),
                               pack4_bf16(v[0], v[1], v[2], v[3]),
                               __ATOMIC_RELAXED, __HIP_MEMORY_SCOPE_AGENT);
        }

        asm volatile("s_waitcnt vmcnt(0)" ::: "memory");   // ring stores at MALL
        __syncthreads();                                   // all waves acked
        if (tid == 0)
            __hip_atomic_store(ep_self, (unsigned)(s + 1),
                               __ATOMIC_RELAXED, __HIP_MEMORY_SCOPE_AGENT);

        // ---- f32 outputs (off critical path, after signal) ----
        if (layer == 1) {
            *(float4*)(out + (size_t)s * BH + (size_t)rg * HID + nb) =
                make_float4(v[0], v[1], v[2], v[3]);
            if (s == SEQ - 1)
                *(float4*)(out + (size_t)SEQ * BH + BH + (size_t)rg * HID + nb) =
                    make_float4(v[0], v[1], v[2], v[3]);     // h_final[1]
        } else if (s == SEQ - 1) {
            *(float4*)(out + (size_t)SEQ * BH + (size_t)rg * HID + nb) =
                make_float4(v[0], v[1], v[2], v[3]);         // h_final[0]
        }
    }
}

extern "C" void kernel_launch(void* const* d_in, const int* in_sizes, int n_in,
                              void* d_out, int out_size, void* d_ws, size_t ws_size,
                              hipStream_t stream) {
    const float* xp   = (const float*)d_in[0];
    const float* Wi0p = (const float*)d_in[1];
    const float* bi0p = (const float*)d_in[2];
    const float* Wh0p = (const float*)d_in[3];
    const float* bh0p = (const float*)d_in[4];
    const float* Wi1p = (const float*)d_in[5];
    const float* bi1p = (const float*)d_in[6];
    const float* Wh1p = (const float*)d_in[7];
    const float* bh1p = (const float*)d_in[8];
    float* outp = (float*)d_out;

    // ws layout: rings 2 MiB | flags 4 KiB | xb 64 MiB
    unsigned short* rings = (unsigned short*)d_ws;
    const size_t ring_bytes = (size_t)2 * DEPTH * BH * sizeof(unsigned short); // 2 MiB
    unsigned int* flags = (unsigned int*)((char*)d_ws + ring_bytes);
    const size_t flag_pad = 4096;
    unsigned short* xb = (unsigned short*)((char*)d_ws + ring_bytes + flag_pad);
    const size_t xb_bytes = (size_t)SEQ * BH * 2;                              // 64 MiB
    const int use_xb = (ws_size >= ring_bytes + flag_pad + xb_bytes) ? 1 : 0;

    {
        const int n16 = (int)((ring_bytes + flag_pad) / 16);
        init_ws<<<(n16 + 255) / 256, 256, 0, stream>>>((uint4*)d_ws, n16);
    }
    if (use_xb)
        cvt_f32_bf16<<<2048, 256, 0, stream>>>(xp, xb, SEQ * BH / 4);

    rnn_mfma<<<dim3(64), dim3(512), 0, stream>>>(
        xp, xb, use_xb,
        Wi0p, bi0p, Wh0p, bh0p, Wi1p, bi1p, Wh1p, bh1p,
        outp, rings, flags);
}

// Round 11
// 5133.895 us; speedup vs baseline: 1.7260x; 1.7260x over previous
//
#include <hip/hip_runtime.h>

// Two-layer tanh RNN, persistent kernel (plain launch), MFMA bf16, epoch sync.
// Round-11 = round-9 structure (proven 4.52ms) + three deltas:
//   (a) u16 epochs: group = 64 x u16 = 128B -> 8-dwordx4 min-scan (was 16).
//   (b) L0 fused dual-group wait: both scans in ONE batch, one vmcnt(0)+SB.
//       DEPTH 4->8 so WAR target (s-7) is rarely binding.
//   (c) ring matmul software-pipelined: 4 chunks x 4 ks, counted vmcnt(8)
//       (T3/T4) -> only first chunk pays the MALL roundtrip. Counted waits
//       are safe vs older outstanding VMEM (vmcnt retires oldest-first).
//
// 256 WGs x 256 thr (1/CU): wg = layer*128 + m_blk*64 + n_blk.
//   Wave wv: src=wv>>1, kh=wv&1; weights VGPR-resident 16 x short8 = 64 VGPRs.
// L0: src0 = x@Wi0 (plain loads, no wait), src1 = h1[s-1]@Wh0 (critical).
// L1: src1 = h2[s-1]@Wh1 (early), src0 = h1[s]@Wi1 (critical).
// Cross-wave K-reduce via LDS, 2 barriers/step. Rule-18 discipline everywhere.
//   L0@s: fused wait grpL0>=s && grpL1>=s-7; L1@s: grpL1>=s then grpL0>=s+1.

#define SEQ 512
#define BATCH 64
#define HID 1024
#define BH (BATCH * HID)
#define DEPTH 8

typedef __attribute__((ext_vector_type(8))) short short8;
typedef __attribute__((ext_vector_type(4))) float f32x4;
typedef __attribute__((ext_vector_type(4))) unsigned int u32x4;

__device__ __forceinline__ unsigned short f32_to_bf16_rne(float f) {
    unsigned int u = __float_as_uint(f);
    u += 0x7FFFu + ((u >> 16) & 1u);
    return (unsigned short)(u >> 16);
}

__device__ __forceinline__ short8 cvt8(float4 f0, float4 f1) {
    short8 w;
    w[0] = (short)f32_to_bf16_rne(f0.x);
    w[1] = (short)f32_to_bf16_rne(f0.y);
    w[2] = (short)f32_to_bf16_rne(f0.z);
    w[3] = (short)f32_to_bf16_rne(f0.w);
    w[4] = (short)f32_to_bf16_rne(f1.x);
    w[5] = (short)f32_to_bf16_rne(f1.y);
    w[6] = (short)f32_to_bf16_rne(f1.z);
    w[7] = (short)f32_to_bf16_rne(f1.w);
    return w;
}

// 16B device-coherent load (served at MALL), pipelineable; caller waits.
__device__ __forceinline__ void ld_cc16(short8& d, const unsigned short* p) {
    asm volatile("global_load_dwordx4 %0, %1, off sc0 sc1"
                 : "=v"(d) : "v"(p) : "memory");
}

__device__ __forceinline__ void vm_wait0() {
    asm volatile("s_waitcnt vmcnt(0)" ::: "memory");
    __builtin_amdgcn_sched_barrier(0);   // rule 18
}
__device__ __forceinline__ void vm_wait8() {
    asm volatile("s_waitcnt vmcnt(8)" ::: "memory");
    __builtin_amdgcn_sched_barrier(0);   // rule 18
}

// u16 epoch store, device-coherent, fire-and-forget
__device__ __forceinline__ void st_ep16(unsigned short* p, unsigned v) {
    asm volatile("global_store_short %0, %1, off sc0 sc1"
                 :: "v"(p), "v"(v) : "memory");
}

__device__ __forceinline__ unsigned long long pack4_bf16(float a, float b, float c, float d) {
    return (unsigned long long)f32_to_bf16_rne(a)
         | ((unsigned long long)f32_to_bf16_rne(b) << 16)
         | ((unsigned long long)f32_to_bf16_rne(c) << 32)
         | ((unsigned long long)f32_to_bf16_rne(d) << 48);
}

__device__ __forceinline__ unsigned min_u16x4(u32x4 w, unsigned mn) {
    #pragma unroll
    for (int j = 0; j < 4; ++j) {
        unsigned lo = w[j] & 0xFFFFu, hi = w[j] >> 16;
        mn = mn < lo ? mn : lo;
        mn = mn < hi ? mn : hi;
    }
    return mn;
}

// single-group wait: 64 u16 slots = 128B = 8 dwordx4, one roundtrip per poll
__device__ __forceinline__ void wait_one(const unsigned short* f, int target) {
    if (target <= 0) return;
    for (;;) {
        u32x4 r[8];
        #pragma unroll
        for (int i = 0; i < 8; ++i)
            asm volatile("global_load_dwordx4 %0, %1, off sc0 sc1"
                         : "=v"(r[i]) : "v"((const unsigned int*)f + i * 4) : "memory");
        asm volatile("s_waitcnt vmcnt(0)" ::: "memory");
        __builtin_amdgcn_sched_barrier(0);
        unsigned mn = 0xFFFFu;
        #pragma unroll
        for (int i = 0; i < 8; ++i) mn = min_u16x4(r[i], mn);
        if ((int)mn >= target) return;
        __builtin_amdgcn_s_sleep(1);
    }
}

// fused dual-group wait (L0): both scans in one batch, one roundtrip
__device__ __forceinline__ void wait_two(const unsigned short* f0, int t0,
                                         const unsigned short* f1, int t1) {
    if (t0 <= 0 && t1 <= 0) return;
    for (;;) {
        u32x4 r0[8], r1[8];
        #pragma unroll
        for (int i = 0; i < 8; ++i)
            asm volatile("global_load_dwordx4 %0, %1, off sc0 sc1"
                         : "=v"(r0[i]) : "v"((const unsigned int*)f0 + i * 4) : "memory");
        #pragma unroll
        for (int i = 0; i < 8; ++i)
            asm volatile("global_load_dwordx4 %0, %1, off sc0 sc1"
                         : "=v"(r1[i]) : "v"((const unsigned int*)f1 + i * 4) : "memory");
        asm volatile("s_waitcnt vmcnt(0)" ::: "memory");
        __builtin_amdgcn_sched_barrier(0);
        unsigned m0 = 0xFFFFu, m1 = 0xFFFFu;
        #pragma unroll
        for (int i = 0; i < 8; ++i) { m0 = min_u16x4(r0[i], m0); m1 = min_u16x4(r1[i], m1); }
        if ((int)m0 >= t0 && (int)m1 >= t1) return;
        __builtin_amdgcn_s_sleep(1);
    }
}

#define MFMA16(W, A, ACC) \
    ACC = __builtin_amdgcn_mfma_f32_16x16x32_bf16((W), (A), (ACC), 0, 0, 0)

// 16-ks ring matmul, 4 chunks x 4 ks, 1-deep pipelined with counted vmcnt.
// Peak in-flight: 16 short8 buffers (64 VGPRs).
__device__ __forceinline__ void ring_mm(const unsigned short* pr,
                                        size_t aoff0, size_t aoff1,
                                        const short8* wreg,
                                        f32x4& acc0, f32x4& acc1) {
    short8 a0[4], a1[4], b0[4], b1[4];
    #pragma unroll
    for (int k = 0; k < 4; ++k) {            // issue c0 (ks 0..3)
        ld_cc16(a0[k], pr + aoff0 + k * 32);
        ld_cc16(a1[k], pr + aoff1 + k * 32);
    }
    #pragma unroll
    for (int k = 0; k < 4; ++k) {            // issue c1 (ks 4..7)
        ld_cc16(b0[k], pr + aoff0 + (4 + k) * 32);
        ld_cc16(b1[k], pr + aoff1 + (4 + k) * 32);
    }
    vm_wait8();                              // c0 complete
    #pragma unroll
    for (int k = 0; k < 4; ++k) { MFMA16(wreg[k], a0[k], acc0); MFMA16(wreg[k], a1[k], acc1); }
    #pragma unroll
    for (int k = 0; k < 4; ++k) {            // issue c2 (ks 8..11)
        ld_cc16(a0[k], pr + aoff0 + (8 + k) * 32);
        ld_cc16(a1[k], pr + aoff1 + (8 + k) * 32);
    }
    vm_wait8();                              // c1 complete
    #pragma unroll
    for (int k = 0; k < 4; ++k) { MFMA16(wreg[4 + k], b0[k], acc0); MFMA16(wreg[4 + k], b1[k], acc1); }
    #pragma unroll
    for (int k = 0; k < 4; ++k) {            // issue c3 (ks 12..15)
        ld_cc16(b0[k], pr + aoff0 + (12 + k) * 32);
        ld_cc16(b1[k], pr + aoff1 + (12 + k) * 32);
    }
    vm_wait8();                              // c2 complete
    #pragma unroll
    for (int k = 0; k < 4; ++k) { MFMA16(wreg[8 + k], a0[k], acc0); MFMA16(wreg[8 + k], a1[k], acc1); }
    vm_wait0();                              // c3 complete
    #pragma unroll
    for (int k = 0; k < 4; ++k) { MFMA16(wreg[12 + k], b0[k], acc0); MFMA16(wreg[12 + k], b1[k], acc1); }
}

__global__ void cvt_f32_bf16(const float* __restrict__ src,
                             unsigned short* __restrict__ dst, int n4) {
    int i = blockIdx.x * blockDim.x + threadIdx.x;
    int stride = gridDim.x * blockDim.x;
    for (; i < n4; i += stride) {
        float4 f = ((const float4*)src)[i];
        ushort4 o;
        o.x = f32_to_bf16_rne(f.x);
        o.y = f32_to_bf16_rne(f.y);
        o.z = f32_to_bf16_rne(f.z);
        o.w = f32_to_bf16_rne(f.w);
        ((ushort4*)dst)[i] = o;
    }
}

__global__ void init_ws(uint4* __restrict__ p, int n16) {
    int i = blockIdx.x * blockDim.x + threadIdx.x;
    if (i < n16) p[i] = make_uint4(0u, 0u, 0u, 0u);
}

__global__ __launch_bounds__(256, 1) void rnn_mfma(
    const float* __restrict__ x,
    const unsigned short* __restrict__ xb, int use_xb,
    const float* __restrict__ Wi0, const float* __restrict__ bi0,
    const float* __restrict__ Wh0, const float* __restrict__ bh0,
    const float* __restrict__ Wi1, const float* __restrict__ bi1,
    const float* __restrict__ Wh1, const float* __restrict__ bh1,
    float* __restrict__ out,
    unsigned short* __restrict__ rings,
    unsigned short* __restrict__ flags)
{
    unsigned short* h1ring = rings;                  // [8][64][1024] bf16
    unsigned short* h2ring = rings + DEPTH * BH;     // [8][64][1024] bf16

    const int tid   = threadIdx.x;
    const int wg    = blockIdx.x;        // 0..255
    const int layer = wg >> 7;           // 0/1
    const int m_blk = (wg >> 6) & 1;     // 0/1 (32 rows)
    const int n_blk = wg & 63;           // 0..63 (16 feats)
    const int wv    = tid >> 6;
    const int lane  = tid & 63;
    const int src   = wv >> 1;           // 0: first source, 1: second
    const int kh    = wv & 1;            // K half
    const int koff  = kh * 512;

    unsigned short* grpL0 = flags + (0 * 2 + m_blk) * 64;   // 128B per group
    unsigned short* grpL1 = flags + (1 * 2 + m_blk) * 64;
    unsigned short* ep_self = (layer ? grpL1 : grpL0) + n_blk;

    // ---- resident weights: 16 short8 = 64 VGPRs ----
    const float* Wsel = layer ? (src ? Wh1 : Wi1) : (src ? Wh0 : Wi0);
    const int f_w  = n_blk * 16 + (lane & 15);
    const int kcb  = koff + (lane >> 4) * 8;
    short8 wreg[16];
    {
        const float* rw = Wsel + (size_t)f_w * HID + kcb;
        #pragma unroll
        for (int ks = 0; ks < 16; ++ks)
            wreg[ks] = cvt8(*(const float4*)(rw + ks * 32),
                            *(const float4*)(rw + ks * 32 + 4));
    }

    // activation (B-operand) addresses
    const int arow0 = m_blk * 32 + (lane & 15);
    const int arow1 = arow0 + 16;
    const size_t aoff0 = (size_t)arow0 * HID + kcb;
    const size_t aoff1 = (size_t)arow1 * HID + kcb;

    // reduce-phase constants (tid<128: one (4-feat group, row) pack)
    const int r_row = tid & 31;          // 0..31
    const int r_fg  = (tid >> 5) & 3;    // 0..3
    const int nb    = n_blk * 16 + r_fg * 4;
    const int rg    = m_blk * 32 + r_row;
    const float* biv = layer ? bi1 : bi0;
    const float* bhv = layer ? bh1 : bh0;
    float bias4[4];
    #pragma unroll
    for (int j = 0; j < 4; ++j) bias4[j] = biv[nb + j] + bhv[nb + j];

    __shared__ float red[4][16][33];

    for (int s = 0; s < SEQ; ++s) {
        f32x4 acc0 = {0.f, 0.f, 0.f, 0.f};
        f32x4 acc1 = {0.f, 0.f, 0.f, 0.f};

        if (layer == 0 && src == 0) {
            // ---- x_s @ Wi0^T : static input, plain loads, no wait ----
            if (use_xb) {
                const unsigned short* px = xb + (size_t)s * BH;
                #pragma unroll
                for (int ks = 0; ks < 16; ++ks) {
                    short8 a0 = *(const short8*)(px + aoff0 + ks * 32);
                    short8 a1 = *(const short8*)(px + aoff1 + ks * 32);
                    MFMA16(wreg[ks], a0, acc0);
                    MFMA16(wreg[ks], a1, acc1);
                }
            } else {
                const float* px = x + (size_t)s * BH;
                #pragma unroll
                for (int ks = 0; ks < 16; ++ks) {
                    short8 a0 = cvt8(*(const float4*)(px + aoff0 + ks * 32),
                                     *(const float4*)(px + aoff0 + ks * 32 + 4));
                    short8 a1 = cvt8(*(const float4*)(px + aoff1 + ks * 32),
                                     *(const float4*)(px + aoff1 + ks * 32 + 4));
                    MFMA16(wreg[ks], a0, acc0);
                    MFMA16(wreg[ks], a1, acc1);
                }
            }
        } else {
            // ---- ring-sourced matmul: wait, then pipelined loads ----
            const unsigned short* pr;
            if (layer == 0) {            // h1[s-1] @ Wh0^T (critical)
                if (lane == 0)
                    wait_two(grpL0, s, grpL1, s - (DEPTH - 1));
                pr = h1ring + (size_t)((s - 1) & (DEPTH - 1)) * BH;
            } else if (src == 1) {       // h2[s-1] @ Wh1^T (early)
                if (lane == 0) wait_one(grpL1, s);
                pr = h2ring + (size_t)((s - 1) & (DEPTH - 1)) * BH;
            } else {                     // h1[s] @ Wi1^T (critical)
                if (lane == 0) wait_one(grpL0, s + 1);
                pr = h1ring + (size_t)(s & (DEPTH - 1)) * BH;
            }
            ring_mm(pr, aoff0, aoff1, wreg, acc0, acc1);
        }

        // ---- partials to LDS: D row = feat 4*(lane>>4)+r, col = batch row ----
        #pragma unroll
        for (int r = 0; r < 4; ++r) {
            red[wv][4 * (lane >> 4) + r][lane & 15]        = acc0[r];
            red[wv][4 * (lane >> 4) + r][16 + (lane & 15)] = acc1[r];
        }
        __syncthreads();

        // ---- reduce + tanh + ring store (tid<128) ----
        float v[4];
        if (tid < 128) {
            #pragma unroll
            for (int j = 0; j < 4; ++j) {
                const int ff = r_fg * 4 + j;
                float sum = red[0][ff][r_row] + red[1][ff][r_row]
                          + red[2][ff][r_row] + red[3][ff][r_row] + bias4[j];
                v[j] = tanhf(sum);
            }
            unsigned short* ring_self =
                (layer ? h2ring : h1ring) + (size_t)(s & (DEPTH - 1)) * BH;
            __hip_atomic_store((unsigned long long*)(ring_self + (size_t)rg * HID + nb),
                               pack4_bf16(v[0], v[1], v[2], v[3]),
                               __ATOMIC_RELAXED, __HIP_MEMORY_SCOPE_AGENT);
        }

        asm volatile("s_waitcnt vmcnt(0)" ::: "memory");   // ring stores at MALL
        __syncthreads();                                   // all waves acked
        if (tid == 0)
            st_ep16(ep_self, (unsigned)(s + 1));

        // ---- f32 outputs (off critical path, after signal) ----
        if (tid < 128) {
            if (layer == 1) {
                *(float4*)(out + (size_t)s * BH + (size_t)rg * HID + nb) =
                    make_float4(v[0], v[1], v[2], v[3]);
                if (s == SEQ - 1)
                    *(float4*)(out + (size_t)SEQ * BH + BH + (size_t)rg * HID + nb) =
                        make_float4(v[0], v[1], v[2], v[3]);     // h_final[1]
            } else if (s == SEQ - 1) {
                *(float4*)(out + (size_t)SEQ * BH + (size_t)rg * HID + nb) =
                    make_float4(v[0], v[1], v[2], v[3]);         // h_final[0]
            }
        }
    }
}

extern "C" void kernel_launch(void* const* d_in, const int* in_sizes, int n_in,
                              void* d_out, int out_size, void* d_ws, size_t ws_size,
                              hipStream_t stream) {
    const float* xp   = (const float*)d_in[0];
    const float* Wi0p = (const float*)d_in[1];
    const float* bi0p = (const float*)d_in[2];
    const float* Wh0p = (const float*)d_in[3];
    const float* bh0p = (const float*)d_in[4];
    const float* Wi1p = (const float*)d_in[5];
    const float* bi1p = (const float*)d_in[6];
    const float* Wh1p = (const float*)d_in[7];
    const float* bh1p = (const float*)d_in[8];
    float* outp = (float*)d_out;

    // ws layout: rings 2 MiB | flags 512B (pad 4 KiB) | xb 64 MiB
    unsigned short* rings = (unsigned short*)d_ws;
    const size_t ring_bytes = (size_t)2 * DEPTH * BH * sizeof(unsigned short); // 2 MiB
    unsigned short* flags = (unsigned short*)((char*)d_ws + ring_bytes);
    const size_t flag_pad = 4096;
    unsigned short* xb = (unsigned short*)((char*)d_ws + ring_bytes + flag_pad);
    const size_t xb_bytes = (size_t)SEQ * BH * 2;                              // 64 MiB
    const int use_xb = (ws_size >= ring_bytes + flag_pad + xb_bytes) ? 1 : 0;

    {
        const int n16 = (int)((ring_bytes + flag_pad) / 16);
        init_ws<<<(n16 + 255) / 256, 256, 0, stream>>>((uint4*)d_ws, n16);
    }
    if (use_xb)
        cvt_f32_bf16<<<2048, 256, 0, stream>>>(xp, xb, SEQ * BH / 4);

    rnn_mfma<<<dim3(256), dim3(256), 0, stream>>>(
        xp, xb, use_xb,
        Wi0p, bi0p, Wh0p, bh0p, Wi1p, bi1p, Wh1p, bh1p,
        outp, rings, flags);
}

// Round 12
// 3856.653 us; speedup vs baseline: 2.2977x; 1.3312x over previous
//
#include <hip/hip_runtime.h>

// Two-layer tanh RNN, persistent kernel (plain launch), MFMA bf16, epoch sync.
// Round-12: batch-diagonal row-groups + fat WGs to shrink the sync domain.
//   256 WGs x 512 thr (8 waves): wg = layer*128 + rg4*32 + nb32.
//   rg4: 4 independent row-groups of 16 batch rows; nb32: 32-feat block.
//   Sync domain = 32 WGs (was 64); detect = one 64B u16 scan.
//   Wave wv: fb=wv>>2 (16-feat half), src=(wv>>1)&1, kh=wv&1.
//   Weights VGPR-resident 16 x short8 = 64 VGPRs; ONE 16-row tile per wave ->
//   ring matmul = 16 coherent loads in ONE batch (1 MALL roundtrip) + 16 MFMA.
//   L1's h2-part (src1) and h1[s]-part (src0) run CONCURRENTLY on different
//   waves, each with its own lane0 wait (wave-divergence sync).
// Ring: 8-deep; WAR: L0 src1 also waits epL1 >= s-7.
//   L0 src1@s: epL0>=s && epL1>=s-7 (fused scan). L1 src1@s: epL1>=s.
//   L1 src0@s: epL0>=s+1.
// Producer: LDS reduce -> tanh -> u16 ring stores (sc0 sc1) -> vmcnt(0) ->
// barrier -> tid0 epoch store. Rule-18 sched_barrier after every asm wait.

#define SEQ 512
#define BATCH 64
#define HID 1024
#define BH (BATCH * HID)
#define DEPTH 8

typedef __attribute__((ext_vector_type(8))) short short8;
typedef __attribute__((ext_vector_type(4))) float f32x4;
typedef __attribute__((ext_vector_type(4))) unsigned int u32x4;

__device__ __forceinline__ unsigned short f32_to_bf16_rne(float f) {
    unsigned int u = __float_as_uint(f);
    u += 0x7FFFu + ((u >> 16) & 1u);
    return (unsigned short)(u >> 16);
}

__device__ __forceinline__ short8 cvt8(float4 f0, float4 f1) {
    short8 w;
    w[0] = (short)f32_to_bf16_rne(f0.x);
    w[1] = (short)f32_to_bf16_rne(f0.y);
    w[2] = (short)f32_to_bf16_rne(f0.z);
    w[3] = (short)f32_to_bf16_rne(f0.w);
    w[4] = (short)f32_to_bf16_rne(f1.x);
    w[5] = (short)f32_to_bf16_rne(f1.y);
    w[6] = (short)f32_to_bf16_rne(f1.z);
    w[7] = (short)f32_to_bf16_rne(f1.w);
    return w;
}

// 16B device-coherent load (served at MALL), pipelineable; caller waits.
__device__ __forceinline__ void ld_cc16(short8& d, const unsigned short* p) {
    asm volatile("global_load_dwordx4 %0, %1, off sc0 sc1"
                 : "=v"(d) : "v"(p) : "memory");
}

__device__ __forceinline__ void vm_wait0() {
    asm volatile("s_waitcnt vmcnt(0)" ::: "memory");
    __builtin_amdgcn_sched_barrier(0);   // rule 18
}

// u16 device-coherent store (epochs, ring values)
__device__ __forceinline__ void st_cc16(unsigned short* p, unsigned v) {
    asm volatile("global_store_short %0, %1, off sc0 sc1"
                 :: "v"(p), "v"(v) : "memory");
}

__device__ __forceinline__ unsigned min_u16x4(u32x4 w, unsigned mn) {
    #pragma unroll
    for (int j = 0; j < 4; ++j) {
        unsigned lo = w[j] & 0xFFFFu, hi = w[j] >> 16;
        mn = mn < lo ? mn : lo;
        mn = mn < hi ? mn : hi;
    }
    return mn;
}

// wait on one group: 32 u16 slots = 64B = 4 dwordx4, one roundtrip per poll
__device__ __forceinline__ void wait_one32(const unsigned short* f, int target) {
    if (target <= 0) return;
    for (;;) {
        u32x4 r[4];
        #pragma unroll
        for (int i = 0; i < 4; ++i)
            asm volatile("global_load_dwordx4 %0, %1, off sc0 sc1"
                         : "=v"(r[i]) : "v"((const unsigned int*)f + i * 4) : "memory");
        asm volatile("s_waitcnt vmcnt(0)" ::: "memory");
        __builtin_amdgcn_sched_barrier(0);
        unsigned mn = 0xFFFFu;
        #pragma unroll
        for (int i = 0; i < 4; ++i) mn = min_u16x4(r[i], mn);
        if ((int)mn >= target) return;
        __builtin_amdgcn_s_sleep(1);
    }
}

// fused dual-group wait: both 64B scans in one batch, one roundtrip
__device__ __forceinline__ void wait_two32(const unsigned short* f0, int t0,
                                           const unsigned short* f1, int t1) {
    if (t0 <= 0 && t1 <= 0) return;
    for (;;) {
        u32x4 r0[4], r1[4];
        #pragma unroll
        for (int i = 0; i < 4; ++i)
            asm volatile("global_load_dwordx4 %0, %1, off sc0 sc1"
                         : "=v"(r0[i]) : "v"((const unsigned int*)f0 + i * 4) : "memory");
        #pragma unroll
        for (int i = 0; i < 4; ++i)
            asm volatile("global_load_dwordx4 %0, %1, off sc0 sc1"
                         : "=v"(r1[i]) : "v"((const unsigned int*)f1 + i * 4) : "memory");
        asm volatile("s_waitcnt vmcnt(0)" ::: "memory");
        __builtin_amdgcn_sched_barrier(0);
        unsigned m0 = 0xFFFFu, m1 = 0xFFFFu;
        #pragma unroll
        for (int i = 0; i < 4; ++i) { m0 = min_u16x4(r0[i], m0); m1 = min_u16x4(r1[i], m1); }
        if ((int)m0 >= t0 && (int)m1 >= t1) return;
        __builtin_amdgcn_s_sleep(1);
    }
}

#define MFMA16(W, A, ACC) \
    ACC = __builtin_amdgcn_mfma_f32_16x16x32_bf16((W), (A), (ACC), 0, 0, 0)

// 16-ks ring matmul, ONE load batch (single MALL roundtrip) + 16 MFMA.
__device__ __forceinline__ void ring_mm16(const unsigned short* pr, size_t aoff,
                                          const short8* wreg, f32x4& acc) {
    short8 a[16];
    #pragma unroll
    for (int k = 0; k < 16; ++k)
        ld_cc16(a[k], pr + aoff + k * 32);
    vm_wait0();
    #pragma unroll
    for (int k = 0; k < 16; ++k)
        MFMA16(wreg[k], a[k], acc);
}

__global__ void cvt_f32_bf16(const float* __restrict__ src,
                             unsigned short* __restrict__ dst, int n4) {
    int i = blockIdx.x * blockDim.x + threadIdx.x;
    int stride = gridDim.x * blockDim.x;
    for (; i < n4; i += stride) {
        float4 f = ((const float4*)src)[i];
        ushort4 o;
        o.x = f32_to_bf16_rne(f.x);
        o.y = f32_to_bf16_rne(f.y);
        o.z = f32_to_bf16_rne(f.z);
        o.w = f32_to_bf16_rne(f.w);
        ((ushort4*)dst)[i] = o;
    }
}

__global__ void init_ws(uint4* __restrict__ p, int n16) {
    int i = blockIdx.x * blockDim.x + threadIdx.x;
    if (i < n16) p[i] = make_uint4(0u, 0u, 0u, 0u);
}

__global__ __launch_bounds__(512, 1) void rnn_mfma(
    const float* __restrict__ x,
    const unsigned short* __restrict__ xb, int use_xb,
    const float* __restrict__ Wi0, const float* __restrict__ bi0,
    const float* __restrict__ Wh0, const float* __restrict__ bh0,
    const float* __restrict__ Wi1, const float* __restrict__ bi1,
    const float* __restrict__ Wh1, const float* __restrict__ bh1,
    float* __restrict__ out,
    unsigned short* __restrict__ rings,
    unsigned short* __restrict__ flags)
{
    unsigned short* h1ring = rings;                  // [8][64][1024] bf16
    unsigned short* h2ring = rings + DEPTH * BH;     // [8][64][1024] bf16

    const int tid   = threadIdx.x;
    const int wg    = blockIdx.x;        // 0..255
    const int layer = wg >> 7;           // 0/1
    const int rg4   = (wg >> 5) & 3;     // row-group: 16 batch rows
    const int nb32  = wg & 31;           // 32-feat block
    const int wv    = tid >> 6;          // 0..7
    const int lane  = tid & 63;
    const int fb    = wv >> 2;           // 16-feat half (0/1)
    const int srcw  = (wv >> 1) & 1;     // 0: first source, 1: recurrent
    const int kh    = wv & 1;            // K half

    unsigned short* gL0 = flags + (0 * 4 + rg4) * 64;   // 128B-strided groups
    unsigned short* gL1 = flags + (1 * 4 + rg4) * 64;
    unsigned short* ep_self = (layer ? gL1 : gL0) + nb32;

    // ---- resident weights: 16 short8 = 64 VGPRs ----
    const float* Wsel = layer ? (srcw ? Wh1 : Wi1) : (srcw ? Wh0 : Wi0);
    const int f_w = nb32 * 32 + fb * 16 + (lane & 15);
    const int kcb = kh * 512 + (lane >> 4) * 8;
    short8 wreg[16];
    {
        const float* rw = Wsel + (size_t)f_w * HID + kcb;
        #pragma unroll
        for (int ks = 0; ks < 16; ++ks)
            wreg[ks] = cvt8(*(const float4*)(rw + ks * 32),
                            *(const float4*)(rw + ks * 32 + 4));
    }

    // activation (B-operand) address: one 16-row tile
    const int arow = rg4 * 16 + (lane & 15);
    const size_t aoff = (size_t)arow * HID + kcb;

    // reduce-phase constants: thread -> (feat 0..31, row 0..15)
    const int r_feat = tid & 31;
    const int r_row  = tid >> 5;
    const int gf     = nb32 * 32 + r_feat;          // global feature
    const int grow   = rg4 * 16 + r_row;            // global batch row
    const float* biv = layer ? bi1 : bi0;
    const float* bhv = layer ? bh1 : bh0;
    const float biasv = biv[gf] + bhv[gf];
    const int rw_base = (r_feat >> 4) * 4;          // partial waves fb*4..+3

    __shared__ float red[8][16][17];                // 8.7 KB

    for (int s = 0; s < SEQ; ++s) {
        f32x4 acc = {0.f, 0.f, 0.f, 0.f};

        if (layer == 0 && srcw == 0) {
            // ---- x_s @ Wi0^T : static input, plain loads, no wait ----
            if (use_xb) {
                const unsigned short* px = xb + (size_t)s * BH + aoff;
                #pragma unroll
                for (int ks = 0; ks < 16; ++ks) {
                    short8 a = *(const short8*)(px + ks * 32);
                    MFMA16(wreg[ks], a, acc);
                }
            } else {
                const float* px = x + (size_t)s * BH + aoff;
                #pragma unroll
                for (int ks = 0; ks < 16; ++ks) {
                    short8 a = cvt8(*(const float4*)(px + ks * 32),
                                    *(const float4*)(px + ks * 32 + 4));
                    MFMA16(wreg[ks], a, acc);
                }
            }
        } else if (layer == 0) {
            // ---- h1[s-1] @ Wh0^T (critical; + ring WAR check) ----
            if (lane == 0) wait_two32(gL0, s, gL1, s - (DEPTH - 1));
            ring_mm16(h1ring + (size_t)((s - 1) & (DEPTH - 1)) * BH, aoff, wreg, acc);
        } else if (srcw == 1) {
            // ---- h2[s-1] @ Wh1^T (own-group recurrent) ----
            if (lane == 0) wait_one32(gL1, s);
            ring_mm16(h2ring + (size_t)((s - 1) & (DEPTH - 1)) * BH, aoff, wreg, acc);
        } else {
            // ---- h1[s] @ Wi1^T (critical cross-layer) ----
            if (lane == 0) wait_one32(gL0, s + 1);
            ring_mm16(h1ring + (size_t)(s & (DEPTH - 1)) * BH, aoff, wreg, acc);
        }

        // ---- partials to LDS: red[wave][feat16][row16] ----
        #pragma unroll
        for (int r = 0; r < 4; ++r)
            red[wv][4 * (lane >> 4) + r][lane & 15] = acc[r];
        __syncthreads();

        // ---- reduce (4 partials) + tanh + u16 ring store: all 512 thr ----
        float v;
        {
            const int ff = r_feat & 15;
            v = red[rw_base][ff][r_row] + red[rw_base + 1][ff][r_row]
              + red[rw_base + 2][ff][r_row] + red[rw_base + 3][ff][r_row] + biasv;
            v = tanhf(v);
            unsigned short* ring_self =
                (layer ? h2ring : h1ring) + (size_t)(s & (DEPTH - 1)) * BH;
            st_cc16(ring_self + (size_t)grow * HID + gf, f32_to_bf16_rne(v));
        }

        asm volatile("s_waitcnt vmcnt(0)" ::: "memory");   // ring stores at MALL
        __builtin_amdgcn_sched_barrier(0);
        __syncthreads();                                   // all waves acked
        if (tid == 0)
            st_cc16(ep_self, (unsigned)(s + 1));

        // ---- f32 outputs (off critical path, after signal) ----
        if (layer == 1) {
            out[(size_t)s * BH + (size_t)grow * HID + gf] = v;
            if (s == SEQ - 1)
                out[(size_t)SEQ * BH + BH + (size_t)grow * HID + gf] = v;  // h_final[1]
        } else if (s == SEQ - 1) {
            out[(size_t)SEQ * BH + (size_t)grow * HID + gf] = v;           // h_final[0]
        }
    }
}

extern "C" void kernel_launch(void* const* d_in, const int* in_sizes, int n_in,
                              void* d_out, int out_size, void* d_ws, size_t ws_size,
                              hipStream_t stream) {
    const float* xp   = (const float*)d_in[0];
    const float* Wi0p = (const float*)d_in[1];
    const float* bi0p = (const float*)d_in[2];
    const float* Wh0p = (const float*)d_in[3];
    const float* bh0p = (const float*)d_in[4];
    const float* Wi1p = (const float*)d_in[5];
    const float* bi1p = (const float*)d_in[6];
    const float* Wh1p = (const float*)d_in[7];
    const float* bh1p = (const float*)d_in[8];
    float* outp = (float*)d_out;

    // ws layout: rings 2 MiB | flags 1 KiB (pad 4 KiB) | xb 64 MiB
    unsigned short* rings = (unsigned short*)d_ws;
    const size_t ring_bytes = (size_t)2 * DEPTH * BH * sizeof(unsigned short); // 2 MiB
    unsigned short* flags = (unsigned short*)((char*)d_ws + ring_bytes);
    const size_t flag_pad = 4096;
    unsigned short* xb = (unsigned short*)((char*)d_ws + ring_bytes + flag_pad);
    const size_t xb_bytes = (size_t)SEQ * BH * 2;                              // 64 MiB
    const int use_xb = (ws_size >= ring_bytes + flag_pad + xb_bytes) ? 1 : 0;

    {
        const int n16 = (int)((ring_bytes + flag_pad) / 16);
        init_ws<<<(n16 + 255) / 256, 256, 0, stream>>>((uint4*)d_ws, n16);
    }
    if (use_xb)
        cvt_f32_bf16<<<2048, 256, 0, stream>>>(xp, xb, SEQ * BH / 4);

    rnn_mfma<<<dim3(256), dim3(512), 0, stream>>>(
        xp, xb, use_xb,
        Wi0p, bi0p, Wh0p, bh0p, Wi1p, bi1p, Wh1p, bh1p,
        outp, rings, flags);
}